// Round 5
// baseline (387.714 us; speedup 1.0000x reference)
//
#include <hip/hip_runtime.h>
#include <hip/hip_bf16.h>
#include <stdint.h>

#define NN 30000
#define MPAD 30080
#define FI 16
#define EE 300000
#define ETOT (EE + NN)
#define HD 256
#define NH 8
#define CH 32
#define NL 3
#define SS 256
#define KS 128
#define NHC 4
#define HC 64
#define GSB 256
#define RPB 118
#define SCB 118   // scan blocks (118*256 >= NN)

typedef _Float16 half8 __attribute__((ext_vector_type(8)));
typedef _Float16 half4v __attribute__((ext_vector_type(4)));
typedef float f32x4 __attribute__((ext_vector_type(4)));

// ---------------- wave helpers ----------------
__device__ __forceinline__ float wsum(float v) {
#pragma unroll
  for (int d = 1; d < 64; d <<= 1) v += __shfl_xor(v, d);
  return v;
}
__device__ __forceinline__ float wmaxf(float v) {
#pragma unroll
  for (int d = 1; d < 64; d <<= 1) v = fmaxf(v, __shfl_xor(v, d));
  return v;
}

// LN over n channels (128/256), 256 threads call, t<n holds a. 2 barriers.
__device__ __forceinline__ float ln_fast(float a, int t, int n, float* red16,
    const float* __restrict__ G, const float* __restrict__ Be, bool relu)
{
  float av = (t < n) ? a : 0.f;
  float s = wsum(av), s2 = wsum(av * av);
  if ((t & 63) == 0) { red16[t >> 6] = s; red16[8 + (t >> 6)] = s2; }
  __syncthreads();
  float sum = red16[0] + red16[1] + red16[2] + red16[3];
  float sq  = red16[8] + red16[9] + red16[10] + red16[11];
  float mu = sum / n;
  float var = sq / n - mu * mu;
  float o = 0.f;
  if (t < n) {
    o = (a - mu) * rsqrtf(var + 1e-5f) * G[t] + Be[t];
    if (relu) o = fmaxf(o, 0.f);
  }
  __syncthreads();
  return o;
}

// ---------------- weight transpose+convert ----------------
__global__ __launch_bounds__(256) void k_wconv(const float* __restrict__ Wl,
    const float* __restrict__ Wr, _Float16* __restrict__ WT)
{
  int m = blockIdx.x >> 8;
  int n = blockIdx.x & 255;
  int k = threadIdx.x;
  int l = m >> 1;
  const float* W = (m & 1) ? (Wr + (size_t)l * HD * HD) : (Wl + (size_t)l * HD * HD);
  WT[((size_t)m * HD + n) * HD + k] = (_Float16)W[k * HD + n];
}

// ---------------- pre-transform ----------------
__global__ __launch_bounds__(256) void k_pre(const float* __restrict__ x,
    const float* __restrict__ W, const float* __restrict__ b,
    _Float16* __restrict__ H16)
{
  __shared__ float Ws[FI][HD];
  __shared__ float xs[8][FI];
  int r0 = blockIdx.x * 8;
  int t = threadIdx.x;
  for (int i = t; i < FI * HD; i += 256) Ws[i >> 8][i & 255] = W[i];
  if (t < 8 * FI) xs[t >> 4][t & 15] = x[(size_t)(r0 + (t >> 4)) * FI + (t & 15)];
  __syncthreads();
  float bj = b[t];
  for (int r = 0; r < 8; ++r) {
    float acc = bj;
#pragma unroll
    for (int k = 0; k < FI; ++k) acc += xs[r][k] * Ws[k][t];
    H16[(size_t)(r0 + r) * HD + t] = (_Float16)acc;
  }
}

// ---------------- CSR build ----------------
__global__ __launch_bounds__(256) void k_count(const int* __restrict__ ei, int* __restrict__ cnt)
{
  int i = blockIdx.x * 256 + threadIdx.x;
  if (i >= ETOT) return;
  int dst = (i < EE) ? ei[EE + i] : (i - EE);
  atomicAdd(&cnt[dst], 1);
}

// block-local exclusive scan; rowptr[i] = local excl, btot[b] = block total
__global__ __launch_bounds__(256) void k_scanA(const int* __restrict__ cnt,
    int* __restrict__ rowptr, int* __restrict__ btot)
{
  __shared__ int wt[4];
  int b = blockIdx.x, t = threadIdx.x;
  int i = b * 256 + t;
  int v = (i < NN) ? cnt[i] : 0;
  int lane = t & 63, w = t >> 6;
  int s = v;
#pragma unroll
  for (int d = 1; d < 64; d <<= 1) {
    int u = __shfl_up(s, d);
    if (lane >= d) s += u;
  }
  if (lane == 63) wt[w] = s;
  __syncthreads();
  int off = 0;
  for (int k = 0; k < w; ++k) off += wt[k];
  if (i < NN) rowptr[i] = off + s - v;
  if (t == 255) btot[b] = off + s;
}

__global__ __launch_bounds__(128) void k_scanB(const int* __restrict__ btot,
    int* __restrict__ boff, int* __restrict__ rowptr)
{
  __shared__ int wt[2];
  int t = threadIdx.x;
  int v = (t < SCB) ? btot[t] : 0;
  int lane = t & 63, w = t >> 6;
  int s = v;
#pragma unroll
  for (int d = 1; d < 64; d <<= 1) {
    int u = __shfl_up(s, d);
    if (lane >= d) s += u;
  }
  if (lane == 63) wt[w] = s;
  __syncthreads();
  int off = (w == 1) ? wt[0] : 0;
  if (t < SCB) boff[t] = off + s - v;
  if (t == 127) rowptr[NN] = wt[0] + wt[1];
}

__global__ __launch_bounds__(256) void k_scanC(int* __restrict__ rowptr,
    const int* __restrict__ boff, int* __restrict__ wptr)
{
  int b = blockIdx.x, t = threadIdx.x;
  int i = b * 256 + t;
  if (i < NN) {
    int r = rowptr[i] + boff[b];
    rowptr[i] = r;
    wptr[i] = r;
  }
}

__global__ __launch_bounds__(256) void k_scatter(const int* __restrict__ ei,
    int* __restrict__ wptr, int* __restrict__ csr_src)
{
  int i = blockIdx.x * 256 + threadIdx.x;
  if (i >= ETOT) return;
  int src = (i < EE) ? ei[i] : (i - EE);
  int dst = (i < EE) ? ei[EE + i] : (i - EE);
  int pos = atomicAdd(&wptr[dst], 1);
  csr_src[pos] = src;
}

// ---------------- fp16 MFMA GEMM ----------------
#define BK 64
__global__ __launch_bounds__(256) void k_gemm16(const _Float16* __restrict__ A,
    const _Float16* __restrict__ WT,
    _Float16* __restrict__ Xl, _Float16* __restrict__ Xr)
{
  __shared__ __align__(16) _Float16 As[128 * BK];
  __shared__ __align__(16) _Float16 Bs[128 * BK];
  int t = threadIdx.x;
  int w = t >> 6, lane = t & 63;
  int row0 = blockIdx.x * 128;
  int ct = blockIdx.y;
  const _Float16* Bmat = WT + (size_t)(ct >> 1) * HD * HD + (size_t)(ct & 1) * 128 * HD;
  _Float16* Out = (ct >> 1) ? Xr : Xl;
  int j0 = (ct & 1) * 128;

  f32x4 acc[4][4] = {};
  int wr = w >> 1, wc = w & 1;

  for (int k0 = 0; k0 < HD; k0 += BK) {
#pragma unroll
    for (int i = 0; i < 4; ++i) {
      int p = (i * 4 + w) * 64 + lane;
      int row = p >> 3, s = p & 7;
      int g = s ^ (row & 7);
      const _Float16* srcA = A + (size_t)(row0 + row) * HD + k0 + g * 8;
      __builtin_amdgcn_global_load_lds(
        (const __attribute__((address_space(1))) void*)srcA,
        (__attribute__((address_space(3))) void*)((char*)As + (i * 4 + w) * 1024),
        16, 0, 0);
      const _Float16* srcB = Bmat + (size_t)row * HD + k0 + g * 8;
      __builtin_amdgcn_global_load_lds(
        (const __attribute__((address_space(1))) void*)srcB,
        (__attribute__((address_space(3))) void*)((char*)Bs + (i * 4 + w) * 1024),
        16, 0, 0);
    }
    __syncthreads();
#pragma unroll
    for (int ks = 0; ks < 2; ++ks) {
      half8 af[4], bfr[4];
      int kslot = ks * 4 + (lane >> 4);
#pragma unroll
      for (int mi = 0; mi < 4; ++mi) {
        int rl = wr * 64 + mi * 16 + (lane & 15);
        int ps = kslot ^ (rl & 7);
        af[mi] = *(const half8*)((const char*)As + rl * 128 + ps * 16);
      }
#pragma unroll
      for (int ni = 0; ni < 4; ++ni) {
        int nl = wc * 64 + ni * 16 + (lane & 15);
        int ps = kslot ^ (nl & 7);
        bfr[ni] = *(const half8*)((const char*)Bs + nl * 128 + ps * 16);
      }
#pragma unroll
      for (int mi = 0; mi < 4; ++mi)
#pragma unroll
        for (int ni = 0; ni < 4; ++ni)
          acc[mi][ni] = __builtin_amdgcn_mfma_f32_16x16x32_f16(af[mi], bfr[ni], acc[mi][ni], 0, 0, 0);
    }
    __syncthreads();
  }
  int crow = (lane >> 4) * 4;
  int ccol = lane & 15;
#pragma unroll
  for (int mi = 0; mi < 4; ++mi)
#pragma unroll
    for (int ni = 0; ni < 4; ++ni) {
      size_t base_r = row0 + wr * 64 + mi * 16 + crow;
      int c = j0 + wc * 64 + ni * 16 + ccol;
#pragma unroll
      for (int r = 0; r < 4; ++r)
        Out[(base_r + r) * HD + c] = (_Float16)acc[mi][ni][r];
    }
}

// ---------------- fused edge + online-softmax agg (defer-max) ----------------
__global__ __launch_bounds__(256) void k_edgeagg(const _Float16* __restrict__ Xl,
    const _Float16* __restrict__ Xr, const float* __restrict__ attw,
    const float* __restrict__ bias, const int* __restrict__ rowptr,
    const int* __restrict__ csr_src, _Float16* __restrict__ H16)
{
  int node = blockIdx.x * 4 + (threadIdx.x >> 6);
  int lane = threadIdx.x & 63;
  if (node >= NN) return;
  int st = rowptr[node], en = rowptr[node + 1];
  int c = lane * 4;
  half4v xrv = *(const half4v*)(Xr + (size_t)node * HD + c);
  float r0 = (float)xrv[0], r1 = (float)xrv[1], r2 = (float)xrv[2], r3 = (float)xrv[3];
  float4 wv = *(const float4*)(attw + c);
  float mh = -1e30f, dsum = 0.f;
  float a0 = 0.f, a1 = 0.f, a2 = 0.f, a3 = 0.f;

  half4v v0 = *(const half4v*)(Xl + (size_t)csr_src[st] * HD + c);
  half4v v1 = {};
  if (st + 1 < en) v1 = *(const half4v*)(Xl + (size_t)csr_src[st + 1] * HD + c);

  for (int i = st; i < en; i += 2) {
    bool has1 = (i + 1 < en);
    half4v p0 = {}, p1 = {};
    if (i + 2 < en) p0 = *(const half4v*)(Xl + (size_t)csr_src[i + 2] * HD + c);
    if (i + 3 < en) p1 = *(const half4v*)(Xl + (size_t)csr_src[i + 3] * HD + c);

    float x00 = (float)v0[0], x01 = (float)v0[1], x02 = (float)v0[2], x03 = (float)v0[3];
    float x10 = (float)v1[0], x11 = (float)v1[1], x12 = (float)v1[2], x13 = (float)v1[3];

    float m, e0 = 0.f, e1 = 0.f;
    m = x00 + r0; m = (m > 0.f) ? m : 0.2f * m; e0 += wv.x * m;
    m = x01 + r1; m = (m > 0.f) ? m : 0.2f * m; e0 += wv.y * m;
    m = x02 + r2; m = (m > 0.f) ? m : 0.2f * m; e0 += wv.z * m;
    m = x03 + r3; m = (m > 0.f) ? m : 0.2f * m; e0 += wv.w * m;
    m = x10 + r0; m = (m > 0.f) ? m : 0.2f * m; e1 += wv.x * m;
    m = x11 + r1; m = (m > 0.f) ? m : 0.2f * m; e1 += wv.y * m;
    m = x12 + r2; m = (m > 0.f) ? m : 0.2f * m; e1 += wv.z * m;
    m = x13 + r3; m = (m > 0.f) ? m : 0.2f * m; e1 += wv.w * m;
    e0 += __shfl_xor(e0, 1); e1 += __shfl_xor(e1, 1);
    e0 += __shfl_xor(e0, 2); e1 += __shfl_xor(e1, 2);
    e0 += __shfl_xor(e0, 4); e1 += __shfl_xor(e1, 4);
    if (!has1) e1 = -1e30f;

    float pmax = fmaxf(e0, e1);
    if (__any(pmax > mh + 8.f)) {
      float nm = fmaxf(mh, pmax);
      float sc = __expf(mh - nm);
      a0 *= sc; a1 *= sc; a2 *= sc; a3 *= sc; dsum *= sc;
      mh = nm;
    }
    float pw0 = __expf(e0 - mh);
    float pw1 = __expf(e1 - mh);
    a0 += pw0 * x00 + pw1 * x10;
    a1 += pw0 * x01 + pw1 * x11;
    a2 += pw0 * x02 + pw1 * x12;
    a3 += pw0 * x03 + pw1 * x13;
    dsum += pw0 + pw1;
    v0 = p0; v1 = p1;
  }
  float inv = 1.f / (dsum + 1e-16f);
  float4 bb = *(const float4*)(bias + c);
  float o0 = a0 * inv + bb.x, o1 = a1 * inv + bb.y;
  float o2 = a2 * inv + bb.z, o3 = a3 * inv + bb.w;
  o0 = (o0 > 0.f) ? o0 : expm1f(o0);
  o1 = (o1 > 0.f) ? o1 : expm1f(o1);
  o2 = (o2 > 0.f) ? o2 : expm1f(o2);
  o3 = (o3 > 0.f) ? o3 : expm1f(o3);
  half4v h4;
  h4[0] = (_Float16)o0; h4[1] = (_Float16)o1; h4[2] = (_Float16)o2; h4[3] = (_Float16)o3;
  *(half4v*)(H16 + (size_t)node * HD + c) = h4;
}

// ---------------- global sum: per-block partials ----------------
__global__ __launch_bounds__(256) void k_gsum(const _Float16* __restrict__ H,
    const int* __restrict__ batch, float* __restrict__ gpart, int* __restrict__ gcnt)
{
  __shared__ float flagf[RPB];
  __shared__ int scount;
  int b = blockIdx.x, t = threadIdx.x;
  int r0 = b * RPB;
  int nr = NN - r0; if (nr > RPB) nr = RPB; if (nr < 0) nr = 0;
  if (t == 0) scount = 0;
  __syncthreads();
  if (t < nr) {
    int ok = (batch[r0 + t] == 0) ? 1 : 0;
    flagf[t] = (float)ok;
    if (ok) atomicAdd(&scount, 1);
  }
  __syncthreads();
  float a0 = 0.f, a1 = 0.f, a2 = 0.f, a3 = 0.f;
  const _Float16* Hp = H + (size_t)r0 * HD + t;
  int r = 0;
  for (; r + 4 <= nr; r += 4) {
    float v0 = (float)Hp[(size_t)(r + 0) * HD];
    float v1 = (float)Hp[(size_t)(r + 1) * HD];
    float v2 = (float)Hp[(size_t)(r + 2) * HD];
    float v3 = (float)Hp[(size_t)(r + 3) * HD];
    a0 += v0 * flagf[r + 0]; a1 += v1 * flagf[r + 1];
    a2 += v2 * flagf[r + 2]; a3 += v3 * flagf[r + 3];
  }
  for (; r < nr; ++r) a0 += (float)Hp[(size_t)r * HD] * flagf[r];
  gpart[(size_t)b * HD + t] = (a0 + a1) + (a2 + a3);
  if (t == 0 && scount) atomicAdd(gcnt, scount);
}

__global__ __launch_bounds__(256) void k_gfin(const float* __restrict__ gpart,
    const int* __restrict__ gcnt, float* __restrict__ gvec)
{
  int t = threadIdx.x;
  float a0 = 0.f, a1 = 0.f, a2 = 0.f, a3 = 0.f;
  for (int b = 0; b < GSB; b += 4) {
    a0 += gpart[(size_t)b * HD + t];
    a1 += gpart[(size_t)(b + 1) * HD + t];
    a2 += gpart[(size_t)(b + 2) * HD + t];
    a3 += gpart[(size_t)(b + 3) * HD + t];
  }
  gvec[t] = ((a0 + a1) + (a2 + a3)) / (float)(*gcnt);
}

// ---------------- tail1: sheet pool + geo encoder + Q/K/V (256 thr) ----------------
__global__ __launch_bounds__(256) void k_tail1(const _Float16* __restrict__ h16,
    const int* __restrict__ sheet_idx, const float* __restrict__ sheet_feat,
    const float* __restrict__ geo_W1, const float* __restrict__ geo_b1,
    const float* __restrict__ geo_g1, const float* __restrict__ geo_be1,
    const float* __restrict__ geo_W2, const float* __restrict__ geo_b2,
    const float* __restrict__ geo_g2, const float* __restrict__ geo_be2,
    const float* __restrict__ ca_Wq, const float* __restrict__ ca_bq,
    const float* __restrict__ ca_Wk, const float* __restrict__ ca_bk,
    const float* __restrict__ ca_Wv, const float* __restrict__ ca_bv,
    float* __restrict__ qb, float* __restrict__ kb, float* __restrict__ vb)
{
  __shared__ float sh[HD];
  __shared__ float g1v[HD];
  __shared__ float g2v[HD];
  __shared__ float xf[FI];
  __shared__ int sidx[KS];
  __shared__ float red16[16];
  int s = blockIdx.x, t = threadIdx.x;

  if (t < KS) sidx[t] = sheet_idx[s * KS + t];
  if (t >= 240) xf[t - 240] = sheet_feat[s * FI + (t - 240)];
  __syncthreads();

  // sheet pool: 8 independent accumulators -> 8 loads in flight
  float pa[8] = {};
#pragma unroll 2
  for (int r = 0; r < KS; r += 8) {
#pragma unroll
    for (int u = 0; u < 8; ++u)
      pa[u] += (float)h16[(size_t)sidx[r + u] * HD + t];
  }
  sh[t] = ((pa[0] + pa[1]) + (pa[2] + pa[3]) + (pa[4] + pa[5]) + (pa[6] + pa[7])) * (1.f / KS);

  // geo1
  float a = geo_b1[t];
#pragma unroll
  for (int k = 0; k < FI; ++k) a += xf[k] * geo_W1[k * HD + t];
  float g1 = ln_fast(a, t, 256, red16, geo_g1, geo_be1, true);
  g1v[t] = g1;
  __syncthreads();

  // geo2
  a = geo_b2[t];
#pragma unroll 8
  for (int k = 0; k < HD; ++k) a += g1v[k] * geo_W2[(size_t)k * HD + t];
  float g2 = ln_fast(a, t, 256, red16, geo_g2, geo_be2, true);
  g2v[t] = g2;
  __syncthreads();

  // q/k/v
  float aq = ca_bq[t], ak = ca_bk[t], av = ca_bv[t];
#pragma unroll 4
  for (int k = 0; k < HD; ++k) {
    float shk = sh[k], g2k = g2v[k];
    aq += shk * ca_Wq[(size_t)k * HD + t];
    ak += g2k * ca_Wk[(size_t)k * HD + t];
    av += g2k * ca_Wv[(size_t)k * HD + t];
  }
  qb[(size_t)s * HD + t] = aq;
  kb[(size_t)s * HD + t] = ak;
  vb[(size_t)s * HD + t] = av;
}

// ---------------- tail2: cross-attn + q-MLP (+done at blk==SS), 256 thr ----------------
__global__ __launch_bounds__(256) void k_tail2(const float* __restrict__ qb,
    const float* __restrict__ kb, const float* __restrict__ vb,
    const float* __restrict__ ca_Wo, const float* __restrict__ ca_bo,
    const float* __restrict__ gvec,
    const float* __restrict__ q_W1, const float* __restrict__ q_b1,
    const float* __restrict__ q_g1, const float* __restrict__ q_be1,
    const float* __restrict__ q_W2, const float* __restrict__ q_b2,
    const float* __restrict__ q_g2, const float* __restrict__ q_be2,
    const float* __restrict__ q_W3, const float* __restrict__ q_b3,
    const float* __restrict__ d_W1, const float* __restrict__ d_b1,
    const float* __restrict__ d_g1, const float* __restrict__ d_be1,
    const float* __restrict__ d_W2, const float* __restrict__ d_b2,
    float* __restrict__ out_q, float* __restrict__ out_d)
{
  __shared__ float qv[HD];
  __shared__ float gv[HD];
  __shared__ float pvs[HD];
  __shared__ float fu[HD];
  __shared__ float hq1[HD];
  __shared__ float redc[256];
  __shared__ float red16[16];
  int blk = blockIdx.x, t = threadIdx.x;
  int w = t >> 6, lane = t & 63;

  if (blk == SS) {
    // ---- done predictor ----
    qv[t] = gvec[t];
    __syncthreads();
    int j2 = t & 127, half = t >> 7;
    float p = 0.f;
#pragma unroll 8
    for (int k = half * 128; k < half * 128 + 128; ++k) p += qv[k] * d_W1[(size_t)k * 128 + j2];
    redc[t] = p;
    __syncthreads();
    float a = 0.f;
    if (t < 128) a = d_b1[t] + redc[t] + redc[128 + t];
    float hd = ln_fast(a, t, 128, red16, d_g1, d_be1, true);
    float vterm = (t < 128) ? hd * d_W2[t] : 0.f;
    float ss = wsum(vterm);
    if ((t & 63) == 0) red16[t >> 6] = ss;
    __syncthreads();
    if (t == 0) out_d[0] = red16[0] + red16[1] + red16[2] + red16[3] + d_b2[0];
    return;
  }

  qv[t] = qb[(size_t)blk * HD + t];
  gv[t] = gvec[t];
  __syncthreads();

  // scores: wave w = head w; lane handles keys {kg*64+lane}
  float e[4];
#pragma unroll
  for (int kg = 0; kg < 4; ++kg) {
    int key = kg * 64 + lane;
    const float4* kr = (const float4*)(kb + (size_t)key * HD + w * HC);
    const float4* qr = (const float4*)(qv + w * HC);
    float acc = 0.f;
#pragma unroll
    for (int d = 0; d < 16; ++d) {
      float4 kk = kr[d], qq = qr[d];
      acc += qq.x * kk.x + qq.y * kk.y + qq.z * kk.z + qq.w * kk.w;
    }
    e[kg] = acc * 0.125f;
  }
  float mx = wmaxf(fmaxf(fmaxf(e[0], e[1]), fmaxf(e[2], e[3])));
  float pw[4];
#pragma unroll
  for (int kg = 0; kg < 4; ++kg) pw[kg] = __expf(e[kg] - mx);
  float dsum = wsum((pw[0] + pw[1]) + (pw[2] + pw[3]));
  float inv = 1.f / dsum;

  // pv: channel c = w*64+lane (head w), shfl-broadcast att weights
  float acc = 0.f;
  const float* vcol = vb + (size_t)w * HC + lane;
#pragma unroll
  for (int kg = 0; kg < 4; ++kg) {
    float pk = pw[kg];
    for (int l = 0; l < 64; ++l)
      acc += __shfl(pk, l) * vcol[(size_t)(kg * 64 + l) * HD];
  }
  pvs[w * HC + lane] = acc * inv;
  __syncthreads();

  // fused = pv @ Wo + bo
  float f = ca_bo[t];
#pragma unroll 8
  for (int k = 0; k < HD; ++k) f += pvs[k] * ca_Wo[(size_t)k * HD + t];
  fu[t] = f;
  __syncthreads();

  // hq1 = relu(LN([fu|gv] @ qW1 + b1))
  float a1 = q_b1[t];
#pragma unroll 8
  for (int k = 0; k < HD; ++k) a1 += fu[k] * q_W1[(size_t)k * HD + t];
#pragma unroll 8
  for (int k = 0; k < HD; ++k) a1 += gv[k] * q_W1[(size_t)(HD + k) * HD + t];
  float h1 = ln_fast(a1, t, 256, red16, q_g1, q_be1, true);
  hq1[t] = h1;
  __syncthreads();

  // hq2 = relu(LN(hq1 @ qW2 + b2)); k split in 2 halves
  int j2 = t & 127, half = t >> 7;
  float p = 0.f;
#pragma unroll 8
  for (int k = half * 128; k < half * 128 + 128; ++k) p += hq1[k] * q_W2[(size_t)k * 128 + j2];
  redc[t] = p;
  __syncthreads();
  float a2 = 0.f;
  if (t < 128) a2 = q_b2[t] + redc[t] + redc[128 + t];
  float h2 = ln_fast(a2, t, 128, red16, q_g2, q_be2, true);

  // out = hq2 @ W3 + b3
  float vterm = (t < 128) ? h2 * q_W3[t] : 0.f;
  float ss = wsum(vterm);
  if ((t & 63) == 0) red16[t >> 6] = ss;
  __syncthreads();
  if (t == 0) out_q[blk] = red16[0] + red16[1] + red16[2] + red16[3] + q_b3[0];
}

// =====================================================================
extern "C" void kernel_launch(void* const* d_in, const int* in_sizes, int n_in,
                              void* d_out, int out_size, void* d_ws, size_t ws_size,
                              hipStream_t stream) {
  const float* x      = (const float*)d_in[0];
  const int*   ei     = (const int*)d_in[1];
  const int*   batch  = (const int*)d_in[2];
  const int*   sheet_idx = (const int*)d_in[3];
  const float* sheet_feat = (const float*)d_in[4];
  const float* pre_W  = (const float*)d_in[5];
  const float* pre_b  = (const float*)d_in[6];
  const float* gat_Wl = (const float*)d_in[7];
  const float* gat_Wr = (const float*)d_in[8];
  const float* gat_att = (const float*)d_in[9];
  const float* gat_b  = (const float*)d_in[10];
  const float* geo_W1 = (const float*)d_in[11];
  const float* geo_b1 = (const float*)d_in[12];
  const float* geo_g1 = (const float*)d_in[13];
  const float* geo_be1 = (const float*)d_in[14];
  const float* geo_W2 = (const float*)d_in[15];
  const float* geo_b2 = (const float*)d_in[16];
  const float* geo_g2 = (const float*)d_in[17];
  const float* geo_be2 = (const float*)d_in[18];
  const float* ca_Wq = (const float*)d_in[19];
  const float* ca_bq = (const float*)d_in[20];
  const float* ca_Wk = (const float*)d_in[21];
  const float* ca_bk = (const float*)d_in[22];
  const float* ca_Wv = (const float*)d_in[23];
  const float* ca_bv = (const float*)d_in[24];
  const float* ca_Wo = (const float*)d_in[25];
  const float* ca_bo = (const float*)d_in[26];
  const float* q_W1 = (const float*)d_in[27];
  const float* q_b1 = (const float*)d_in[28];
  const float* q_g1 = (const float*)d_in[29];
  const float* q_be1 = (const float*)d_in[30];
  const float* q_W2 = (const float*)d_in[31];
  const float* q_b2 = (const float*)d_in[32];
  const float* q_g2 = (const float*)d_in[33];
  const float* q_be2 = (const float*)d_in[34];
  const float* q_W3 = (const float*)d_in[35];
  const float* q_b3 = (const float*)d_in[36];
  const float* d_W1 = (const float*)d_in[37];
  const float* d_b1 = (const float*)d_in[38];
  const float* d_g1 = (const float*)d_in[39];
  const float* d_be1 = (const float*)d_in[40];
  const float* d_W2 = (const float*)d_in[41];
  const float* d_b2 = (const float*)d_in[42];

  char* wsb = (char*)d_ws;
  auto alloc = [&](size_t bytes) { char* p = wsb; wsb += (bytes + 255) & ~(size_t)255; return p; };

  _Float16* h16  = (_Float16*)alloc((size_t)MPAD * HD * 2);
  _Float16* Xl16 = (_Float16*)alloc((size_t)MPAD * HD * 2);
  _Float16* Xr16 = (_Float16*)alloc((size_t)MPAD * HD * 2);
  _Float16* WT   = (_Float16*)alloc((size_t)6 * HD * HD * 2);
  float* gpart   = (float*)alloc((size_t)GSB * HD * 4);
  float* gvec    = (float*)alloc(256 * 4);
  float* qb      = (float*)alloc(SS * HD * 4);
  float* kb      = (float*)alloc(SS * HD * 4);
  float* vb      = (float*)alloc(SS * HD * 4);
  int* cnt       = (int*)alloc((size_t)NN * 4);
  int* rowptr    = (int*)alloc((size_t)(NN + 1) * 4);
  int* wptr      = (int*)alloc((size_t)NN * 4);
  int* csr_src   = (int*)alloc((size_t)ETOT * 4);
  int* btot      = (int*)alloc((size_t)SCB * 4);
  int* boff      = (int*)alloc((size_t)SCB * 4);
  int* gcnt      = (int*)alloc(4);

  float* out_q = (float*)d_out;        // [256]
  float* out_d = out_q + SS;           // [1]

  hipMemsetAsync(cnt, 0, (size_t)NN * sizeof(int), stream);
  hipMemsetAsync(gcnt, 0, sizeof(int), stream);
  hipMemsetAsync(h16 + (size_t)NN * HD, 0, (size_t)(MPAD - NN) * HD * 2, stream);

  // CSR build (hierarchical scan)
  k_count<<<(ETOT + 255) / 256, 256, 0, stream>>>(ei, cnt);
  k_scanA<<<SCB, 256, 0, stream>>>(cnt, rowptr, btot);
  k_scanB<<<1, 128, 0, stream>>>(btot, boff, rowptr);
  k_scanC<<<SCB, 256, 0, stream>>>(rowptr, boff, wptr);
  k_scatter<<<(ETOT + 255) / 256, 256, 0, stream>>>(ei, wptr, csr_src);

  // weights + pre-transform
  k_wconv<<<6 * 256, 256, 0, stream>>>(gat_Wl, gat_Wr, WT);
  k_pre<<<NN / 8, 256, 0, stream>>>(x, pre_W, pre_b, h16);

  // GAT layers
  dim3 ggrid(MPAD / 128, 4);
  for (int l = 0; l < NL; ++l) {
    k_gemm16<<<ggrid, 256, 0, stream>>>(h16, WT + (size_t)l * 2 * HD * HD, Xl16, Xr16);
    k_edgeagg<<<(NN + 3) / 4, 256, 0, stream>>>(Xl16, Xr16, gat_att + l * NH * CH,
                                                gat_b + l * HD, rowptr, csr_src, h16);
  }

  // global mean
  k_gsum<<<GSB, 256, 0, stream>>>(h16, batch, gpart, gcnt);
  k_gfin<<<1, 256, 0, stream>>>(gpart, gcnt, gvec);

  // fused tail
  k_tail1<<<SS, 256, 0, stream>>>(h16, sheet_idx, sheet_feat,
      geo_W1, geo_b1, geo_g1, geo_be1, geo_W2, geo_b2, geo_g2, geo_be2,
      ca_Wq, ca_bq, ca_Wk, ca_bk, ca_Wv, ca_bv, qb, kb, vb);
  k_tail2<<<SS + 1, 256, 0, stream>>>(qb, kb, vb, ca_Wo, ca_bo, gvec,
      q_W1, q_b1, q_g1, q_be1, q_W2, q_b2, q_g2, q_be2, q_W3, q_b3,
      d_W1, d_b1, d_g1, d_be1, d_W2, d_b2, out_q, out_d);
}